// Round 1
// 314.156 us; speedup vs baseline: 1.0417x; 1.0417x over previous
//
#include <hip/hip_runtime.h>
#include <hip/hip_fp16.h>
#include <cstdint>
#include <cstddef>

// ---------------------------------------------------------------------------
// LightGCN on MI355X — atomic-free CSR build + fp16 Y-scaled gather storage.
//   Mirror COO: rows=[u, U+it], cols=[U+it, u] — partition reads only the
//     first 2M source pairs and emits both directed edges.
//   Y-substitution: Y_l = diag(deg^-1/2) X_l => Y_{l+1} = (1/deg)*sum Y_l[c]
//     -> SpMM inner loop is a pure gather-sum.
//   SpMM mapping (NEW): 8 rows per wave, 8 lanes per row, 8 dims per lane.
//     Reduction is lane-local (no shuffles); edge loop is branch-free via
//     dummy-column-0 padding (node 0 has deg 0 -> Y[0,:] == 0 every layer).
//     32 edges/iter -> 4 independent dwordx4 gathers in flight per wave.
//   finalize: self-computed bucket prefix, per-row hist/rank -> row_ptr,
//     dis/dis2/invd, cv, fused Y0 convert.
//   gather_logits: one wave per batch element, 3 row-dots + wave dot.
//   6 dispatches total.
// ---------------------------------------------------------------------------

typedef __attribute__((ext_vector_type(8))) _Float16 half8;

#define NB_SHIFT 8
#define BCAP 16000      // max edges per 256-row bucket (expected max ~10.7K)
#define P1_SRC 4096     // source pairs per tile -> 8192 directed edges
#define P1_DIM 512

// ---- partition mirror pairs into fixed-capacity bucket regions ----
__global__ __launch_bounds__(P1_DIM) void partition_kernel(
    const int* __restrict__ rows, const int* __restrict__ cols,
    int* __restrict__ bucket_cursor, int* __restrict__ tmp,
    int M /* = nnz/2 */, int nb) {
    __shared__ int            lhist[1024];
    __shared__ int            loff[1024];
    __shared__ int            ldelta[1024];   // dest_base[b] - loff[b]
    __shared__ int            wsum[8];
    __shared__ int            stage[2 * P1_SRC];   // 32 KB
    __shared__ unsigned short bstage[2 * P1_SRC];  // 16 KB
    int t = threadIdx.x;
    int lane = t & 63, wv = t >> 6;
    int base     = blockIdx.x * P1_SRC;
    int cnt_here = min(P1_SRC, M - base);
    int full4    = cnt_here >> 2;
    int rem      = cnt_here & 3;
    for (int i = t; i < 1024; i += P1_DIM) lhist[i] = 0;
    __syncthreads();
    const int4* rows4 = (const int4*)(rows + base);
    const int4* cols4 = (const int4*)(cols + base);
    int4 uu[2], vv[2];
    int  rka[8], rkb[8];
#pragma unroll
    for (int k = 0; k < 2; ++k) {
        int i4 = t + k * P1_DIM;
        if (i4 < full4) {
            uu[k] = rows4[i4];
            vv[k] = cols4[i4];
            int u4[4] = {uu[k].x, uu[k].y, uu[k].z, uu[k].w};
            int v4[4] = {vv[k].x, vv[k].y, vv[k].z, vv[k].w};
#pragma unroll
            for (int e = 0; e < 4; ++e) {
                rka[4 * k + e] = atomicAdd(&lhist[u4[e] >> NB_SHIFT], 1);
                rkb[4 * k + e] = atomicAdd(&lhist[v4[e] >> NB_SHIFT], 1);
            }
        }
    }
    int ur = 0, vr = 0, rkra = 0, rkrb = 0;
    bool has_rem = (t < rem);
    if (has_rem) {
        ur = rows[base + 4 * full4 + t];
        vr = cols[base + 4 * full4 + t];
        rkra = atomicAdd(&lhist[ur >> NB_SHIFT], 1);
        rkrb = atomicAdd(&lhist[vr >> NB_SHIFT], 1);
    }
    __syncthreads();
    // wave-shuffle exclusive scan over 1024 bucket counts (2 per thread)
    int v0 = lhist[2 * t], v1 = lhist[2 * t + 1];
    int ts = v0 + v1;
    int sc = ts;
#pragma unroll
    for (int off = 1; off < 64; off <<= 1) {
        int x = __shfl_up(sc, off);
        if (lane >= off) sc += x;
    }
    if (lane == 63) wsum[wv] = sc;
    __syncthreads();
    int prefix = 0;
#pragma unroll
    for (int k = 0; k < 8; ++k) {
        int s = wsum[k];
        prefix += (k < wv) ? s : 0;
    }
    int run = prefix + sc - ts;  // exclusive prefix of ts
    loff[2 * t]     = run;
    loff[2 * t + 1] = run + v0;
#pragma unroll
    for (int k = 0; k < 2; ++k) {
        int b  = 2 * t + k;
        int vvk = (k == 0) ? v0 : v1;
        if (b < nb && vvk > 0) {
            int old = atomicAdd(&bucket_cursor[b], vvk);   // delta in bucket
            ldelta[b] = b * BCAP + old - loff[b];
        }
    }
    __syncthreads();
#pragma unroll
    for (int k = 0; k < 2; ++k) {
        int i4 = t + k * P1_DIM;
        if (i4 < full4) {
            int u4[4] = {uu[k].x, uu[k].y, uu[k].z, uu[k].w};
            int v4[4] = {vv[k].x, vv[k].y, vv[k].z, vv[k].w};
#pragma unroll
            for (int e = 0; e < 4; ++e) {
                int ub = u4[e] >> NB_SHIFT;
                int s1 = loff[ub] + rka[4 * k + e];
                stage[s1]  = ((u4[e] & 255) << 18) | v4[e];
                bstage[s1] = (unsigned short)ub;
                int vb = v4[e] >> NB_SHIFT;
                int s2 = loff[vb] + rkb[4 * k + e];
                stage[s2]  = ((v4[e] & 255) << 18) | u4[e];
                bstage[s2] = (unsigned short)vb;
            }
        }
    }
    if (has_rem) {
        int ub = ur >> NB_SHIFT;
        int s1 = loff[ub] + rkra;
        stage[s1]  = ((ur & 255) << 18) | vr;
        bstage[s1] = (unsigned short)ub;
        int vb = vr >> NB_SHIFT;
        int s2 = loff[vb] + rkrb;
        stage[s2]  = ((vr & 255) << 18) | ur;
        bstage[s2] = (unsigned short)vb;
    }
    __syncthreads();
    int total = 2 * cnt_here;
    for (int s = t; s < total; s += P1_DIM) {
        tmp[s + ldelta[bstage[s]]] = stage[s];
    }
}

// ---- per-bucket finalize: self-prefix, row_ptr, dis/dis2/invd, cv, Y0 ----
__global__ __launch_bounds__(256) void finalize_kernel(
    const int* __restrict__ tmp, const int* __restrict__ bcur,
    const float4* __restrict__ ut4, const float4* __restrict__ it4,
    int* __restrict__ row_ptr, float* __restrict__ dis,
    float* __restrict__ dis2, float* __restrict__ invd,
    int* __restrict__ cv, half8* __restrict__ Yh0,
    int usernum, int n_nodes, int nb, int nnz) {
    __shared__ int   rcnt[256];
    __shared__ int   ccur[256];
    __shared__ int   wsum[4];
    __shared__ int   red[256];
    __shared__ float sdis[256];
    int b = blockIdx.x;
    int t = threadIdx.x;
    int lane = t & 63, wv = t >> 6;
    // self-computed exclusive prefix of bcur over buckets < b
    int partial = 0;
    for (int i = t; i < nb; i += 256) {
        int c = bcur[i];
        if (i < b) partial += c;
    }
    red[t] = partial;
    __syncthreads();
    for (int off = 128; off > 0; off >>= 1) {
        if (t < off) red[t] += red[t + off];
        __syncthreads();
    }
    int dbeg  = red[0];
    int count = bcur[b];
    int src   = b * BCAP;
    rcnt[t] = 0;
    __syncthreads();
    for (int i = t; i < count; i += 256) {
        atomicAdd(&rcnt[tmp[src + i] >> 18], 1);
    }
    __syncthreads();
    int v = rcnt[t];
    int sc = v;
#pragma unroll
    for (int off = 1; off < 64; off <<= 1) {
        int x = __shfl_up(sc, off);
        if (lane >= off) sc += x;
    }
    if (lane == 63) wsum[wv] = sc;
    __syncthreads();
    int prefix = 0;
#pragma unroll
    for (int k = 0; k < 4; ++k) {
        int s = wsum[k];
        prefix += (k < wv) ? s : 0;
    }
    int ex = prefix + sc - v;
    ccur[t] = ex;
    int row = (b << NB_SHIFT) + t;
    float dval = 0.0f;
    if (row < n_nodes) {
        row_ptr[row] = dbeg + ex;
        double dv = (double)v;
        dval      = (v > 0) ? (float)(1.0 / sqrt(dv)) : 0.0f;
        dis[row]  = dval;
        dis2[row] = (v > 0) ? (float)(1.0 / dv) : 0.0f;
        invd[row] = (v > 0) ? (float)sqrt(dv) : 0.0f;
    }
    sdis[t] = dval;
    if (b == nb - 1 && t == 0) row_ptr[n_nodes] = nnz;
    __syncthreads();
    // rank + direct cv write: dest window ~28KB -> L2 write-merge
    for (int i = t; i < count; i += 256) {
        int p  = tmp[src + i];
        int rk = atomicAdd(&ccur[p >> 18], 1);
        cv[dbeg + rk] = p & 0x3FFFF;
    }
    // fused convert: Y0[row] = dis[row] * X0[row] (fp16, 128B rows)
    int row0 = b << NB_SHIFT;
    for (int i = t; i < 256 * 8; i += 256) {
        int rl = i >> 3;
        int rg = row0 + rl;
        if (rg < n_nodes) {
            int c = i & 7;
            float d = sdis[rl];
            const float4* srcp = (rg <= usernum)
                ? (ut4 + (size_t)rg * 16 + 2 * c)
                : (it4 + (size_t)(rg - usernum) * 16 + 2 * c);
            float4 a = srcp[0];
            float4 e = srcp[1];
            half8 o;
            o[0] = (_Float16)(d * a.x); o[1] = (_Float16)(d * a.y);
            o[2] = (_Float16)(d * a.z); o[3] = (_Float16)(d * a.w);
            o[4] = (_Float16)(d * e.x); o[5] = (_Float16)(d * e.y);
            o[6] = (_Float16)(d * e.z); o[7] = (_Float16)(d * e.w);
            Yh0[(size_t)rg * 8 + c] = o;
        }
    }
}

// ---- pure gather-sum CSR row: 8 edge-slots x 8 lanes x half8 ----
// (used by gather_logits only) Halving-butterfly reduction: returns ONE
// element per lane, for dim d = l8*8 + k with k = (g&1)*4 + (g&2) + (g>>2).
__device__ inline float csr_row_sum_h(const _Float16* __restrict__ Yh,
                                      const int* __restrict__ cv,
                                      int beg, int end, int g, int l8,
                                      float one) {
    float acc[8] = {0.f, 0.f, 0.f, 0.f, 0.f, 0.f, 0.f, 0.f};
    const char* Yb = (const char*)Yh;
    const char* cb = (const char*)cv;
    unsigned lo = (unsigned)l8 * 16u;
    int j = beg + g;
    for (; j + 8 < end; j += 16) {
        unsigned c0 = (unsigned)*(const int*)(cb + ((unsigned)j << 2));
        unsigned c1 = (unsigned)*(const int*)(cb + ((unsigned)(j + 8) << 2));
        half8 x0 = *(const half8*)(Yb + (c0 << 7) + lo);
        half8 x1 = *(const half8*)(Yb + (c1 << 7) + lo);
        half8 tt = x0 + x1;   // 4x v_pk_add_f16
#pragma unroll
        for (int k = 0; k < 8; ++k) {
            acc[k] += one * (float)tt[k];   // v_mad_mix_f32
        }
    }
    if (j < end) {
        unsigned c0 = (unsigned)*(const int*)(cb + ((unsigned)j << 2));
        half8 x0 = *(const half8*)(Yb + (c0 << 7) + lo);
#pragma unroll
        for (int k = 0; k < 8; ++k) {
            acc[k] += one * (float)x0[k];
        }
    }
    bool gb0 = (g & 1) != 0;
    bool gb1 = (g & 2) != 0;
    bool gb2 = (g & 4) != 0;
    float s0 = gb0 ? acc[0] : acc[4];
    float s1 = gb0 ? acc[1] : acc[5];
    float s2 = gb0 ? acc[2] : acc[6];
    float s3 = gb0 ? acc[3] : acc[7];
    float a0 = (gb0 ? acc[4] : acc[0]) + __shfl_xor(s0, 8);
    float a1 = (gb0 ? acc[5] : acc[1]) + __shfl_xor(s1, 8);
    float a2 = (gb0 ? acc[6] : acc[2]) + __shfl_xor(s2, 8);
    float a3 = (gb0 ? acc[7] : acc[3]) + __shfl_xor(s3, 8);
    float t0 = gb1 ? a0 : a2;
    float t1 = gb1 ? a1 : a3;
    float b0 = (gb1 ? a2 : a0) + __shfl_xor(t0, 16);
    float b1 = (gb1 ? a3 : a1) + __shfl_xor(t1, 16);
    float u = gb2 ? b0 : b1;
    float fin = (gb2 ? b1 : b0) + __shfl_xor(u, 32);
    return fin;
}

__device__ inline int lane_dim(int g, int l8) {
    return l8 * 8 + ((g & 1) * 4 + (g & 2) + (g >> 2));
}

// ---- SpMM: 8 rows per wave, 8 lanes per row, 8 dims per lane ----
// Y_{l+1}[r][d] = dis2[r] * sum_e Y_l[cv[e]][d]
// Lane (g=lane>>3, sub=lane&7) owns dims [8*sub, 8*sub+8) of row wid*8+g and
// accumulates in registers -> no cross-lane reduction at all.
// Edge loop: 4 edges/group/iter, branch-free: out-of-range edge slots are
// cndmask'd to column 0 (node 0 has degree 0 => Y[0][:] == 0 in every layer,
// and that single line stays L1-hot => dummy gathers are ~free).
// cv must be readable 512B past nnz (padded in the workspace alloc).
__global__ __launch_bounds__(256) void spmm_y_kernel(
    const _Float16* __restrict__ Yin, _Float16* __restrict__ Yout,
    const int* __restrict__ row_ptr, const int* __restrict__ cv,
    const float* __restrict__ dis2, float one, int n_nodes) {
    int wid  = (blockIdx.x * blockDim.x + threadIdx.x) >> 6;
    int lane = threadIdx.x & 63;
    int g = lane >> 3, sub = lane & 7;
    int row = wid * 8 + g;
    bool ok = row < n_nodes;
    int beg = 0, end = 0;
    if (ok) {
        beg = row_ptr[row];
        end = row_ptr[row + 1];
    }
    float d2 = ok ? dis2[row] : 0.0f;
    const char* Yb = (const char*)Yin;
    const char* cb = (const char*)cv;
    unsigned lo = (unsigned)sub * 16u;
    float acc[8] = {0.f, 0.f, 0.f, 0.f, 0.f, 0.f, 0.f, 0.f};
    int j = beg;
    for (;;) {
        if (!__any(j < end)) break;
        unsigned jb = (unsigned)j << 2;
        int r0 = *(const int*)(cb + jb);
        int r1 = *(const int*)(cb + jb + 4u);
        int r2 = *(const int*)(cb + jb + 8u);
        int r3 = *(const int*)(cb + jb + 12u);
        unsigned c0 = (unsigned)((j     < end) ? r0 : 0);
        unsigned c1 = (unsigned)((j + 1 < end) ? r1 : 0);
        unsigned c2 = (unsigned)((j + 2 < end) ? r2 : 0);
        unsigned c3 = (unsigned)((j + 3 < end) ? r3 : 0);
        half8 x0 = *(const half8*)(Yb + (c0 << 7) + lo);
        half8 x1 = *(const half8*)(Yb + (c1 << 7) + lo);
        half8 x2 = *(const half8*)(Yb + (c2 << 7) + lo);
        half8 x3 = *(const half8*)(Yb + (c3 << 7) + lo);
        half8 s01 = x0 + x1;           // v_pk_add_f16
        half8 s23 = x2 + x3;
        half8 tt  = s01 + s23;
#pragma unroll
        for (int k = 0; k < 8; ++k) {
            acc[k] += one * (float)tt[k];   // v_mad_mix_f32
        }
        j += 4;
    }
    if (ok) {
        half8 o;
#pragma unroll
        for (int k = 0; k < 8; ++k) o[k] = (_Float16)(acc[k] * d2);
        *(half8*)((char*)Yout + ((size_t)row << 7) + lo) = o;
    }
}

// fused layer-3 + gather + logits: one wave per batch element.
// emb(idx)[d] = X0fp32[idx][d] + invd*(Y1+Y2)[idx][d] + dis*rowdot(Y2)[d];
// out[b] = <emb(u), emb(pos)>/16; out[B+b] = <emb(u), emb(neg)>/16.
__global__ __launch_bounds__(256) void gather_logits_kernel(
    const float* __restrict__ ut, const float* __restrict__ itb,
    const _Float16* __restrict__ Y1, const _Float16* __restrict__ Y2,
    const int* __restrict__ row_ptr, const int* __restrict__ cv,
    const float* __restrict__ dis, const float* __restrict__ invd,
    const int* __restrict__ user_ids, const int* __restrict__ pos_seqs,
    const int* __restrict__ neg_seqs, float* __restrict__ out,
    float one, int usernum, int itemnum, int batch) {
    int w    = (blockIdx.x * blockDim.x + threadIdx.x) >> 6;
    int lane = threadIdx.x & 63;
    if (w >= batch) return;
    int g = lane >> 3, l8 = lane & 7;
    int d = lane_dim(g, l8);
    int idxs[3];
    int u = min(max(user_ids[w], 0), usernum);
    idxs[0] = u;
    int p = min(max(pos_seqs[w], 1), itemnum);
    idxs[1] = usernum + p;
    int nn = min(max(neg_seqs[w], 1), itemnum);
    idxs[2] = usernum + nn;
    float vals[3];
#pragma unroll
    for (int q = 0; q < 3; ++q) {
        int idx = idxs[q];
        int beg = row_ptr[idx];
        int end = row_ptr[idx + 1];
        float dr = dis[idx];
        float iv = invd[idx];
        float fin = csr_row_sum_h(Y2, cv, beg, end, g, l8, one);
        const float* base0 = (q == 0) ? (ut + (size_t)u * 64)
                                      : (itb + (size_t)(idx - usernum) * 64);
        float x0v = base0[d];
        float y1v = (float)Y1[(size_t)idx * 64 + d];
        float y2v = (float)Y2[(size_t)idx * 64 + d];
        vals[q] = x0v + iv * (y1v + y2v) + fin * dr;
    }
    float dp = vals[0] * vals[1];
    float dn = vals[0] * vals[2];
#pragma unroll
    for (int off = 1; off < 64; off <<= 1) {
        dp += __shfl_xor(dp, off);
        dn += __shfl_xor(dn, off);
    }
    if (lane == 0) {
        out[w]         = dp * 0.0625f;
        out[batch + w] = dn * 0.0625f;
    }
}

extern "C" void kernel_launch(void* const* d_in, const int* in_sizes, int n_in,
                              void* d_out, int out_size, void* d_ws,
                              size_t ws_size, hipStream_t stream) {
    const float* user_table = (const float*)d_in[0];
    const float* item_table = (const float*)d_in[1];
    const int*   rows       = (const int*)d_in[3];
    const int*   cols       = (const int*)d_in[4];
    const int*   user_ids   = (const int*)d_in[5];
    const int*   pos_seqs   = (const int*)d_in[6];
    const int*   neg_seqs   = (const int*)d_in[7];
    float*       out        = (float*)d_out;

    const int D = 64;
    int usernum = in_sizes[0] / D - 1;   // 100000
    int itemnum = in_sizes[1] / D - 1;   // 50000
    int nnz     = in_sizes[2];           // 4,000,000
    int batch   = in_sizes[5];           // 4096
    int n_nodes = usernum + itemnum + 1; // 150001
    int nb      = (n_nodes + (1 << NB_SHIFT) - 1) >> NB_SHIFT;  // 586
    int M       = nnz >> 1;              // 2,000,000 source pairs (mirror COO)

    // ---- workspace layout ----
    char* w = (char*)d_ws;
    auto alloc = [&](size_t bytes) {
        char* p = w;
        w += (bytes + 255) & ~(size_t)255;
        return p;
    };
    _Float16* Yh0   = (_Float16*)alloc((size_t)n_nodes * D * 2);  // 19.2 MB
    _Float16* Yh1   = (_Float16*)alloc((size_t)n_nodes * D * 2);  // 19.2 MB
    _Float16* Yh2   = (_Float16*)alloc((size_t)n_nodes * D * 2);  // 19.2 MB
    int*   cv       = (int*)alloc((size_t)nnz * 4 + 512);         // 16 MB (+pad
                                      // so spmm's padded edge loop can read
                                      // up to 512B past nnz safely)
    int*   row_ptr  = (int*)alloc((size_t)(n_nodes + 1) * 4);
    float* dis      = (float*)alloc((size_t)n_nodes * 4);
    float* dis2     = (float*)alloc((size_t)n_nodes * 4);
    float* invd     = (float*)alloc((size_t)n_nodes * 4);
    int*   bcur     = (int*)alloc(4096);
    // partition scratch: 586*16000*4 = 37.5 MB, aliases Yh1+Yh2 (38.4 MB);
    // dead after finalize; Yh1/Yh2 written only afterwards.
    int*   tmp      = (int*)Yh1;

    // ---- CSR build ----
    hipMemsetAsync(bcur, 0, 4096, stream);
    int p1_tiles = (M + P1_SRC - 1) / P1_SRC;
    partition_kernel<<<p1_tiles, P1_DIM, 0, stream>>>(rows, cols, bcur, tmp,
                                                      M, nb);
    finalize_kernel<<<nb, 256, 0, stream>>>(
        tmp, bcur, (const float4*)user_table, (const float4*)item_table,
        row_ptr, dis, dis2, invd, cv, (half8*)Yh0, usernum, n_nodes, nb, nnz);

    // ---- layers: Yh0 -> Yh1 -> Yh2 (pure gather-sum + 1/deg scale) ----
    const float one = 1.0f;
    int spmm_grid = (n_nodes + 31) / 32;   // 32 rows per 256-thr block
    spmm_y_kernel<<<spmm_grid, 256, 0, stream>>>(Yh0, Yh1, row_ptr, cv, dis2,
                                                 one, n_nodes);
    spmm_y_kernel<<<spmm_grid, 256, 0, stream>>>(Yh1, Yh2, row_ptr, cv, dis2,
                                                 one, n_nodes);

    // ---- fused layer-3 + gather + logits ----
    gather_logits_kernel<<<(batch + 3) / 4, 256, 0, stream>>>(
        user_table, item_table, Yh1, Yh2, row_ptr, cv, dis, invd, user_ids,
        pos_seqs, neg_seqs, out, one, usernum, itemnum, batch);
}

// Round 2
// 302.950 us; speedup vs baseline: 1.0803x; 1.0370x over previous
//
#include <hip/hip_runtime.h>
#include <hip/hip_fp16.h>
#include <cstdint>
#include <cstddef>

// ---------------------------------------------------------------------------
// LightGCN on MI355X — atomic-free CSR build + fp16 Y-scaled gather storage.
//   Mirror COO: rows=[u, U+it], cols=[U+it, u] — partition reads only the
//     first 2M source pairs and emits both directed edges.
//   Y-substitution: Y_l = diag(deg^-1/2) X_l => Y_{l+1} = (1/deg)*sum Y_l[c]
//     -> SpMM inner loop is a pure gather-sum.
//   SpMM mapping: 8 rows per wave, 8 lanes per row, 8 dims per lane.
//     Reduction is lane-local (no shuffles); edge loop is branch-free via
//     dummy-column-0 padding (node 0 has deg 0 -> Y[0,:] == 0 every layer).
//     R2: 8-edge batches (8 gathers in flight/wave), countable loop from
//     wave-max degree (no per-iter __any), cv prefetch registers so the
//     cv->gather dependency hides under accumulate of the previous batch.
//   finalize: self-computed bucket prefix, per-row hist/rank -> row_ptr,
//     dis/dis2/invd, cv, fused Y0 convert.
//   gather_logits: one wave per batch element, 3 row-dots + wave dot.
//   6 dispatches total.
// ---------------------------------------------------------------------------

typedef __attribute__((ext_vector_type(8))) _Float16 half8;

#define NB_SHIFT 8
#define BCAP 16000      // max edges per 256-row bucket (expected max ~10.7K)
#define P1_SRC 4096     // source pairs per tile -> 8192 directed edges
#define P1_DIM 512

// ---- partition mirror pairs into fixed-capacity bucket regions ----
__global__ __launch_bounds__(P1_DIM) void partition_kernel(
    const int* __restrict__ rows, const int* __restrict__ cols,
    int* __restrict__ bucket_cursor, int* __restrict__ tmp,
    int M /* = nnz/2 */, int nb) {
    __shared__ int            lhist[1024];
    __shared__ int            loff[1024];
    __shared__ int            ldelta[1024];   // dest_base[b] - loff[b]
    __shared__ int            wsum[8];
    __shared__ int            stage[2 * P1_SRC];   // 32 KB
    __shared__ unsigned short bstage[2 * P1_SRC];  // 16 KB
    int t = threadIdx.x;
    int lane = t & 63, wv = t >> 6;
    int base     = blockIdx.x * P1_SRC;
    int cnt_here = min(P1_SRC, M - base);
    int full4    = cnt_here >> 2;
    int rem      = cnt_here & 3;
    for (int i = t; i < 1024; i += P1_DIM) lhist[i] = 0;
    __syncthreads();
    const int4* rows4 = (const int4*)(rows + base);
    const int4* cols4 = (const int4*)(cols + base);
    int4 uu[2], vv[2];
    int  rka[8], rkb[8];
#pragma unroll
    for (int k = 0; k < 2; ++k) {
        int i4 = t + k * P1_DIM;
        if (i4 < full4) {
            uu[k] = rows4[i4];
            vv[k] = cols4[i4];
            int u4[4] = {uu[k].x, uu[k].y, uu[k].z, uu[k].w};
            int v4[4] = {vv[k].x, vv[k].y, vv[k].z, vv[k].w};
#pragma unroll
            for (int e = 0; e < 4; ++e) {
                rka[4 * k + e] = atomicAdd(&lhist[u4[e] >> NB_SHIFT], 1);
                rkb[4 * k + e] = atomicAdd(&lhist[v4[e] >> NB_SHIFT], 1);
            }
        }
    }
    int ur = 0, vr = 0, rkra = 0, rkrb = 0;
    bool has_rem = (t < rem);
    if (has_rem) {
        ur = rows[base + 4 * full4 + t];
        vr = cols[base + 4 * full4 + t];
        rkra = atomicAdd(&lhist[ur >> NB_SHIFT], 1);
        rkrb = atomicAdd(&lhist[vr >> NB_SHIFT], 1);
    }
    __syncthreads();
    // wave-shuffle exclusive scan over 1024 bucket counts (2 per thread)
    int v0 = lhist[2 * t], v1 = lhist[2 * t + 1];
    int ts = v0 + v1;
    int sc = ts;
#pragma unroll
    for (int off = 1; off < 64; off <<= 1) {
        int x = __shfl_up(sc, off);
        if (lane >= off) sc += x;
    }
    if (lane == 63) wsum[wv] = sc;
    __syncthreads();
    int prefix = 0;
#pragma unroll
    for (int k = 0; k < 8; ++k) {
        int s = wsum[k];
        prefix += (k < wv) ? s : 0;
    }
    int run = prefix + sc - ts;  // exclusive prefix of ts
    loff[2 * t]     = run;
    loff[2 * t + 1] = run + v0;
#pragma unroll
    for (int k = 0; k < 2; ++k) {
        int b  = 2 * t + k;
        int vvk = (k == 0) ? v0 : v1;
        if (b < nb && vvk > 0) {
            int old = atomicAdd(&bucket_cursor[b], vvk);   // delta in bucket
            ldelta[b] = b * BCAP + old - loff[b];
        }
    }
    __syncthreads();
#pragma unroll
    for (int k = 0; k < 2; ++k) {
        int i4 = t + k * P1_DIM;
        if (i4 < full4) {
            int u4[4] = {uu[k].x, uu[k].y, uu[k].z, uu[k].w};
            int v4[4] = {vv[k].x, vv[k].y, vv[k].z, vv[k].w};
#pragma unroll
            for (int e = 0; e < 4; ++e) {
                int ub = u4[e] >> NB_SHIFT;
                int s1 = loff[ub] + rka[4 * k + e];
                stage[s1]  = ((u4[e] & 255) << 18) | v4[e];
                bstage[s1] = (unsigned short)ub;
                int vb = v4[e] >> NB_SHIFT;
                int s2 = loff[vb] + rkb[4 * k + e];
                stage[s2]  = ((v4[e] & 255) << 18) | u4[e];
                bstage[s2] = (unsigned short)vb;
            }
        }
    }
    if (has_rem) {
        int ub = ur >> NB_SHIFT;
        int s1 = loff[ub] + rkra;
        stage[s1]  = ((ur & 255) << 18) | vr;
        bstage[s1] = (unsigned short)ub;
        int vb = vr >> NB_SHIFT;
        int s2 = loff[vb] + rkrb;
        stage[s2]  = ((vr & 255) << 18) | ur;
        bstage[s2] = (unsigned short)vb;
    }
    __syncthreads();
    int total = 2 * cnt_here;
    for (int s = t; s < total; s += P1_DIM) {
        tmp[s + ldelta[bstage[s]]] = stage[s];
    }
}

// ---- per-bucket finalize: self-prefix, row_ptr, dis/dis2/invd, cv, Y0 ----
__global__ __launch_bounds__(256) void finalize_kernel(
    const int* __restrict__ tmp, const int* __restrict__ bcur,
    const float4* __restrict__ ut4, const float4* __restrict__ it4,
    int* __restrict__ row_ptr, float* __restrict__ dis,
    float* __restrict__ dis2, float* __restrict__ invd,
    int* __restrict__ cv, half8* __restrict__ Yh0,
    int usernum, int n_nodes, int nb, int nnz) {
    __shared__ int   rcnt[256];
    __shared__ int   ccur[256];
    __shared__ int   wsum[4];
    __shared__ int   red[256];
    __shared__ float sdis[256];
    int b = blockIdx.x;
    int t = threadIdx.x;
    int lane = t & 63, wv = t >> 6;
    // self-computed exclusive prefix of bcur over buckets < b
    int partial = 0;
    for (int i = t; i < nb; i += 256) {
        int c = bcur[i];
        if (i < b) partial += c;
    }
    red[t] = partial;
    __syncthreads();
    for (int off = 128; off > 0; off >>= 1) {
        if (t < off) red[t] += red[t + off];
        __syncthreads();
    }
    int dbeg  = red[0];
    int count = bcur[b];
    int src   = b * BCAP;
    rcnt[t] = 0;
    __syncthreads();
    for (int i = t; i < count; i += 256) {
        atomicAdd(&rcnt[tmp[src + i] >> 18], 1);
    }
    __syncthreads();
    int v = rcnt[t];
    int sc = v;
#pragma unroll
    for (int off = 1; off < 64; off <<= 1) {
        int x = __shfl_up(sc, off);
        if (lane >= off) sc += x;
    }
    if (lane == 63) wsum[wv] = sc;
    __syncthreads();
    int prefix = 0;
#pragma unroll
    for (int k = 0; k < 4; ++k) {
        int s = wsum[k];
        prefix += (k < wv) ? s : 0;
    }
    int ex = prefix + sc - v;
    ccur[t] = ex;
    int row = (b << NB_SHIFT) + t;
    float dval = 0.0f;
    if (row < n_nodes) {
        row_ptr[row] = dbeg + ex;
        double dv = (double)v;
        dval      = (v > 0) ? (float)(1.0 / sqrt(dv)) : 0.0f;
        dis[row]  = dval;
        dis2[row] = (v > 0) ? (float)(1.0 / dv) : 0.0f;
        invd[row] = (v > 0) ? (float)sqrt(dv) : 0.0f;
    }
    sdis[t] = dval;
    if (b == nb - 1 && t == 0) row_ptr[n_nodes] = nnz;
    __syncthreads();
    // rank + direct cv write: dest window ~28KB -> L2 write-merge
    for (int i = t; i < count; i += 256) {
        int p  = tmp[src + i];
        int rk = atomicAdd(&ccur[p >> 18], 1);
        cv[dbeg + rk] = p & 0x3FFFF;
    }
    // fused convert: Y0[row] = dis[row] * X0[row] (fp16, 128B rows)
    int row0 = b << NB_SHIFT;
    for (int i = t; i < 256 * 8; i += 256) {
        int rl = i >> 3;
        int rg = row0 + rl;
        if (rg < n_nodes) {
            int c = i & 7;
            float d = sdis[rl];
            const float4* srcp = (rg <= usernum)
                ? (ut4 + (size_t)rg * 16 + 2 * c)
                : (it4 + (size_t)(rg - usernum) * 16 + 2 * c);
            float4 a = srcp[0];
            float4 e = srcp[1];
            half8 o;
            o[0] = (_Float16)(d * a.x); o[1] = (_Float16)(d * a.y);
            o[2] = (_Float16)(d * a.z); o[3] = (_Float16)(d * a.w);
            o[4] = (_Float16)(d * e.x); o[5] = (_Float16)(d * e.y);
            o[6] = (_Float16)(d * e.z); o[7] = (_Float16)(d * e.w);
            Yh0[(size_t)rg * 8 + c] = o;
        }
    }
}

// ---- pure gather-sum CSR row: 8 edge-slots x 8 lanes x half8 ----
// (used by gather_logits only) Halving-butterfly reduction: returns ONE
// element per lane, for dim d = l8*8 + k with k = (g&1)*4 + (g&2) + (g>>2).
__device__ inline float csr_row_sum_h(const _Float16* __restrict__ Yh,
                                      const int* __restrict__ cv,
                                      int beg, int end, int g, int l8,
                                      float one) {
    float acc[8] = {0.f, 0.f, 0.f, 0.f, 0.f, 0.f, 0.f, 0.f};
    const char* Yb = (const char*)Yh;
    const char* cb = (const char*)cv;
    unsigned lo = (unsigned)l8 * 16u;
    int j = beg + g;
    for (; j + 8 < end; j += 16) {
        unsigned c0 = (unsigned)*(const int*)(cb + ((unsigned)j << 2));
        unsigned c1 = (unsigned)*(const int*)(cb + ((unsigned)(j + 8) << 2));
        half8 x0 = *(const half8*)(Yb + (c0 << 7) + lo);
        half8 x1 = *(const half8*)(Yb + (c1 << 7) + lo);
        half8 tt = x0 + x1;   // 4x v_pk_add_f16
#pragma unroll
        for (int k = 0; k < 8; ++k) {
            acc[k] += one * (float)tt[k];   // v_mad_mix_f32
        }
    }
    if (j < end) {
        unsigned c0 = (unsigned)*(const int*)(cb + ((unsigned)j << 2));
        half8 x0 = *(const half8*)(Yb + (c0 << 7) + lo);
#pragma unroll
        for (int k = 0; k < 8; ++k) {
            acc[k] += one * (float)x0[k];
        }
    }
    bool gb0 = (g & 1) != 0;
    bool gb1 = (g & 2) != 0;
    bool gb2 = (g & 4) != 0;
    float s0 = gb0 ? acc[0] : acc[4];
    float s1 = gb0 ? acc[1] : acc[5];
    float s2 = gb0 ? acc[2] : acc[6];
    float s3 = gb0 ? acc[3] : acc[7];
    float a0 = (gb0 ? acc[4] : acc[0]) + __shfl_xor(s0, 8);
    float a1 = (gb0 ? acc[5] : acc[1]) + __shfl_xor(s1, 8);
    float a2 = (gb0 ? acc[6] : acc[2]) + __shfl_xor(s2, 8);
    float a3 = (gb0 ? acc[7] : acc[3]) + __shfl_xor(s3, 8);
    float t0 = gb1 ? a0 : a2;
    float t1 = gb1 ? a1 : a3;
    float b0 = (gb1 ? a2 : a0) + __shfl_xor(t0, 16);
    float b1 = (gb1 ? a3 : a1) + __shfl_xor(t1, 16);
    float u = gb2 ? b0 : b1;
    float fin = (gb2 ? b1 : b0) + __shfl_xor(u, 32);
    return fin;
}

__device__ inline int lane_dim(int g, int l8) {
    return l8 * 8 + ((g & 1) * 4 + (g & 2) + (g >> 2));
}

// ---- SpMM: 8 rows per wave, 8 lanes per row, 8 dims per lane ----
// Y_{l+1}[r][d] = dis2[r] * sum_e Y_l[cv[e]][d]
// Lane (g=lane>>3, sub=lane&7) owns dims [8*sub, 8*sub+8) of row wid*8+g and
// accumulates in registers -> no cross-lane reduction at all.
// R2 edge loop: 8 edges per batch, trip count = wave-max degree (3 shuffles,
// one-time) -> countable loop, no per-iter __any. Out-of-range edge slots
// cndmask to column 0 (node 0 has degree 0 => Y[0][:] == 0 in every layer;
// its single line stays L1-hot => dummy gathers ~free). cv indices for the
// NEXT batch are loaded at the end of the body so the cv->gather dependency
// hides under the current batch's accumulate (counted vmcnt, no full drain).
// cv must be readable ~8KB past nnz (padded in the workspace alloc); garbage
// reads there are masked before use as gather addresses.
__global__ __launch_bounds__(256) void spmm_y_kernel(
    const _Float16* __restrict__ Yin, _Float16* __restrict__ Yout,
    const int* __restrict__ row_ptr, const int* __restrict__ cv,
    const float* __restrict__ dis2, float one, int n_nodes) {
    int wid  = (blockIdx.x * blockDim.x + threadIdx.x) >> 6;
    int lane = threadIdx.x & 63;
    int g = lane >> 3, sub = lane & 7;
    int row = wid * 8 + g;
    bool ok = row < n_nodes;
    int beg = 0, end = 0;
    if (ok) {
        beg = row_ptr[row];
        end = row_ptr[row + 1];
    }
    float d2 = ok ? dis2[row] : 0.0f;
    const char* Yb = (const char*)Yin;
    const char* cb = (const char*)cv;
    unsigned lo = (unsigned)sub * 16u;
    float acc[8] = {0.f, 0.f, 0.f, 0.f, 0.f, 0.f, 0.f, 0.f};
    // wave-max degree -> uniform trip count (lanes within a group agree)
    int len = end - beg;
    int mx = len;
    mx = max(mx, __shfl_xor(mx, 8));
    mx = max(mx, __shfl_xor(mx, 16));
    mx = max(mx, __shfl_xor(mx, 32));
    int iters = (mx + 7) >> 3;
    int j = beg;
    size_t jb = ((size_t)(unsigned)j) << 2;
    int r0 = *(const int*)(cb + jb);
    int r1 = *(const int*)(cb + jb + 4u);
    int r2 = *(const int*)(cb + jb + 8u);
    int r3 = *(const int*)(cb + jb + 12u);
    int r4 = *(const int*)(cb + jb + 16u);
    int r5 = *(const int*)(cb + jb + 20u);
    int r6 = *(const int*)(cb + jb + 24u);
    int r7 = *(const int*)(cb + jb + 28u);
    for (int it = 0; it < iters; ++it) {
        unsigned c0 = (unsigned)((j     < end) ? r0 : 0);
        unsigned c1 = (unsigned)((j + 1 < end) ? r1 : 0);
        unsigned c2 = (unsigned)((j + 2 < end) ? r2 : 0);
        unsigned c3 = (unsigned)((j + 3 < end) ? r3 : 0);
        unsigned c4 = (unsigned)((j + 4 < end) ? r4 : 0);
        unsigned c5 = (unsigned)((j + 5 < end) ? r5 : 0);
        unsigned c6 = (unsigned)((j + 6 < end) ? r6 : 0);
        unsigned c7 = (unsigned)((j + 7 < end) ? r7 : 0);
        half8 x0 = *(const half8*)(Yb + ((size_t)c0 << 7) + lo);
        half8 x1 = *(const half8*)(Yb + ((size_t)c1 << 7) + lo);
        half8 x2 = *(const half8*)(Yb + ((size_t)c2 << 7) + lo);
        half8 x3 = *(const half8*)(Yb + ((size_t)c3 << 7) + lo);
        half8 x4 = *(const half8*)(Yb + ((size_t)c4 << 7) + lo);
        half8 x5 = *(const half8*)(Yb + ((size_t)c5 << 7) + lo);
        half8 x6 = *(const half8*)(Yb + ((size_t)c6 << 7) + lo);
        half8 x7 = *(const half8*)(Yb + ((size_t)c7 << 7) + lo);
        // prefetch next batch's indices (pad-safe past nnz; masked above)
        j += 8;
        jb = ((size_t)(unsigned)j) << 2;
        r0 = *(const int*)(cb + jb);
        r1 = *(const int*)(cb + jb + 4u);
        r2 = *(const int*)(cb + jb + 8u);
        r3 = *(const int*)(cb + jb + 12u);
        r4 = *(const int*)(cb + jb + 16u);
        r5 = *(const int*)(cb + jb + 20u);
        r6 = *(const int*)(cb + jb + 24u);
        r7 = *(const int*)(cb + jb + 28u);
        // pairwise fp16 tree (consumes gathers as they complete, counted
        // vmcnt), then one mad_mix per dim into f32 acc
        half8 sA = (x0 + x1) + (x2 + x3);
        half8 sB = (x4 + x5) + (x6 + x7);
        half8 tt = sA + sB;
#pragma unroll
        for (int k = 0; k < 8; ++k) {
            acc[k] += one * (float)tt[k];   // v_mad_mix_f32
        }
    }
    if (ok) {
        half8 o;
#pragma unroll
        for (int k = 0; k < 8; ++k) o[k] = (_Float16)(acc[k] * d2);
        *(half8*)((char*)Yout + ((size_t)row << 7) + lo) = o;
    }
}

// fused layer-3 + gather + logits: one wave per batch element.
// emb(idx)[d] = X0fp32[idx][d] + invd*(Y1+Y2)[idx][d] + dis*rowdot(Y2)[d];
// out[b] = <emb(u), emb(pos)>/16; out[B+b] = <emb(u), emb(neg)>/16.
__global__ __launch_bounds__(256) void gather_logits_kernel(
    const float* __restrict__ ut, const float* __restrict__ itb,
    const _Float16* __restrict__ Y1, const _Float16* __restrict__ Y2,
    const int* __restrict__ row_ptr, const int* __restrict__ cv,
    const float* __restrict__ dis, const float* __restrict__ invd,
    const int* __restrict__ user_ids, const int* __restrict__ pos_seqs,
    const int* __restrict__ neg_seqs, float* __restrict__ out,
    float one, int usernum, int itemnum, int batch) {
    int w    = (blockIdx.x * blockDim.x + threadIdx.x) >> 6;
    int lane = threadIdx.x & 63;
    if (w >= batch) return;
    int g = lane >> 3, l8 = lane & 7;
    int d = lane_dim(g, l8);
    int idxs[3];
    int u = min(max(user_ids[w], 0), usernum);
    idxs[0] = u;
    int p = min(max(pos_seqs[w], 1), itemnum);
    idxs[1] = usernum + p;
    int nn = min(max(neg_seqs[w], 1), itemnum);
    idxs[2] = usernum + nn;
    float vals[3];
#pragma unroll
    for (int q = 0; q < 3; ++q) {
        int idx = idxs[q];
        int beg = row_ptr[idx];
        int end = row_ptr[idx + 1];
        float dr = dis[idx];
        float iv = invd[idx];
        float fin = csr_row_sum_h(Y2, cv, beg, end, g, l8, one);
        const float* base0 = (q == 0) ? (ut + (size_t)u * 64)
                                      : (itb + (size_t)(idx - usernum) * 64);
        float x0v = base0[d];
        float y1v = (float)Y1[(size_t)idx * 64 + d];
        float y2v = (float)Y2[(size_t)idx * 64 + d];
        vals[q] = x0v + iv * (y1v + y2v) + fin * dr;
    }
    float dp = vals[0] * vals[1];
    float dn = vals[0] * vals[2];
#pragma unroll
    for (int off = 1; off < 64; off <<= 1) {
        dp += __shfl_xor(dp, off);
        dn += __shfl_xor(dn, off);
    }
    if (lane == 0) {
        out[w]         = dp * 0.0625f;
        out[batch + w] = dn * 0.0625f;
    }
}

extern "C" void kernel_launch(void* const* d_in, const int* in_sizes, int n_in,
                              void* d_out, int out_size, void* d_ws,
                              size_t ws_size, hipStream_t stream) {
    const float* user_table = (const float*)d_in[0];
    const float* item_table = (const float*)d_in[1];
    const int*   rows       = (const int*)d_in[3];
    const int*   cols       = (const int*)d_in[4];
    const int*   user_ids   = (const int*)d_in[5];
    const int*   pos_seqs   = (const int*)d_in[6];
    const int*   neg_seqs   = (const int*)d_in[7];
    float*       out        = (float*)d_out;

    const int D = 64;
    int usernum = in_sizes[0] / D - 1;   // 100000
    int itemnum = in_sizes[1] / D - 1;   // 50000
    int nnz     = in_sizes[2];           // 4,000,000
    int batch   = in_sizes[5];           // 4096
    int n_nodes = usernum + itemnum + 1; // 150001
    int nb      = (n_nodes + (1 << NB_SHIFT) - 1) >> NB_SHIFT;  // 586
    int M       = nnz >> 1;              // 2,000,000 source pairs (mirror COO)

    // ---- workspace layout ----
    char* w = (char*)d_ws;
    auto alloc = [&](size_t bytes) {
        char* p = w;
        w += (bytes + 255) & ~(size_t)255;
        return p;
    };
    _Float16* Yh0   = (_Float16*)alloc((size_t)n_nodes * D * 2);  // 19.2 MB
    _Float16* Yh1   = (_Float16*)alloc((size_t)n_nodes * D * 2);  // 19.2 MB
    _Float16* Yh2   = (_Float16*)alloc((size_t)n_nodes * D * 2);  // 19.2 MB
    int*   cv       = (int*)alloc((size_t)nnz * 4 + 8192);        // 16 MB (+pad
                                      // so spmm's wave-max edge loop can read
                                      // cv indices past nnz safely; values
                                      // are masked before use)
    int*   row_ptr  = (int*)alloc((size_t)(n_nodes + 1) * 4);
    float* dis      = (float*)alloc((size_t)n_nodes * 4);
    float* dis2     = (float*)alloc((size_t)n_nodes * 4);
    float* invd     = (float*)alloc((size_t)n_nodes * 4);
    int*   bcur     = (int*)alloc(4096);
    // partition scratch: 586*16000*4 = 37.5 MB, aliases Yh1+Yh2 (38.4 MB);
    // dead after finalize; Yh1/Yh2 written only afterwards.
    int*   tmp      = (int*)Yh1;

    // ---- CSR build ----
    hipMemsetAsync(bcur, 0, 4096, stream);
    int p1_tiles = (M + P1_SRC - 1) / P1_SRC;
    partition_kernel<<<p1_tiles, P1_DIM, 0, stream>>>(rows, cols, bcur, tmp,
                                                      M, nb);
    finalize_kernel<<<nb, 256, 0, stream>>>(
        tmp, bcur, (const float4*)user_table, (const float4*)item_table,
        row_ptr, dis, dis2, invd, cv, (half8*)Yh0, usernum, n_nodes, nb, nnz);

    // ---- layers: Yh0 -> Yh1 -> Yh2 (pure gather-sum + 1/deg scale) ----
    const float one = 1.0f;
    int spmm_grid = (n_nodes + 31) / 32;   // 32 rows per 256-thr block
    spmm_y_kernel<<<spmm_grid, 256, 0, stream>>>(Yh0, Yh1, row_ptr, cv, dis2,
                                                 one, n_nodes);
    spmm_y_kernel<<<spmm_grid, 256, 0, stream>>>(Yh1, Yh2, row_ptr, cv, dis2,
                                                 one, n_nodes);

    // ---- fused layer-3 + gather + logits ----
    gather_logits_kernel<<<(batch + 3) / 4, 256, 0, stream>>>(
        user_table, item_table, Yh1, Yh2, row_ptr, cv, dis, invd, user_ids,
        pos_seqs, neg_seqs, out, one, usernum, itemnum, batch);
}

// Round 3
// 292.412 us; speedup vs baseline: 1.1192x; 1.0360x over previous
//
#include <hip/hip_runtime.h>
#include <hip/hip_fp16.h>
#include <cstdint>
#include <cstddef>

// ---------------------------------------------------------------------------
// LightGCN on MI355X — atomic-free CSR build + fp16 Y-scaled gather storage.
//   Mirror COO: rows=[u, U+it], cols=[U+it, u] — partition reads only the
//     first 2M source pairs and emits both directed edges.
//   Y-substitution: Y_l = diag(deg^-1/2) X_l => Y_{l+1} = (1/deg)*sum Y_l[c]
//     -> SpMM inner loop is a pure gather-sum.
//   SpMM mapping: 8 rows per wave, 8 lanes per row, 8 dims per lane;
//     8-edge batches, countable loop (wave-max degree), cv prefetch regs.
//   R3: finalize split — 512-thread hist/rank blocks (2x waves, half trip
//     counts) + separate wide streaming convert_y0 kernel (was serialized
//     at the tail of every bucket block at 9 waves/CU).
//   7 dispatches total.
// ---------------------------------------------------------------------------

typedef __attribute__((ext_vector_type(8))) _Float16 half8;

#define NB_SHIFT 8
#define BCAP 16000      // max edges per 256-row bucket (expected max ~10.7K)
#define P1_SRC 4096     // source pairs per tile -> 8192 directed edges
#define P1_DIM 512

// ---- partition mirror pairs into fixed-capacity bucket regions ----
__global__ __launch_bounds__(P1_DIM) void partition_kernel(
    const int* __restrict__ rows, const int* __restrict__ cols,
    int* __restrict__ bucket_cursor, int* __restrict__ tmp,
    int M /* = nnz/2 */, int nb) {
    __shared__ int            lhist[1024];
    __shared__ int            loff[1024];
    __shared__ int            ldelta[1024];   // dest_base[b] - loff[b]
    __shared__ int            wsum[8];
    __shared__ int            stage[2 * P1_SRC];   // 32 KB
    __shared__ unsigned short bstage[2 * P1_SRC];  // 16 KB
    int t = threadIdx.x;
    int lane = t & 63, wv = t >> 6;
    int base     = blockIdx.x * P1_SRC;
    int cnt_here = min(P1_SRC, M - base);
    int full4    = cnt_here >> 2;
    int rem      = cnt_here & 3;
    for (int i = t; i < 1024; i += P1_DIM) lhist[i] = 0;
    __syncthreads();
    const int4* rows4 = (const int4*)(rows + base);
    const int4* cols4 = (const int4*)(cols + base);
    int4 uu[2], vv[2];
    int  rka[8], rkb[8];
#pragma unroll
    for (int k = 0; k < 2; ++k) {
        int i4 = t + k * P1_DIM;
        if (i4 < full4) {
            uu[k] = rows4[i4];
            vv[k] = cols4[i4];
            int u4[4] = {uu[k].x, uu[k].y, uu[k].z, uu[k].w};
            int v4[4] = {vv[k].x, vv[k].y, vv[k].z, vv[k].w};
#pragma unroll
            for (int e = 0; e < 4; ++e) {
                rka[4 * k + e] = atomicAdd(&lhist[u4[e] >> NB_SHIFT], 1);
                rkb[4 * k + e] = atomicAdd(&lhist[v4[e] >> NB_SHIFT], 1);
            }
        }
    }
    int ur = 0, vr = 0, rkra = 0, rkrb = 0;
    bool has_rem = (t < rem);
    if (has_rem) {
        ur = rows[base + 4 * full4 + t];
        vr = cols[base + 4 * full4 + t];
        rkra = atomicAdd(&lhist[ur >> NB_SHIFT], 1);
        rkrb = atomicAdd(&lhist[vr >> NB_SHIFT], 1);
    }
    __syncthreads();
    // wave-shuffle exclusive scan over 1024 bucket counts (2 per thread)
    int v0 = lhist[2 * t], v1 = lhist[2 * t + 1];
    int ts = v0 + v1;
    int sc = ts;
#pragma unroll
    for (int off = 1; off < 64; off <<= 1) {
        int x = __shfl_up(sc, off);
        if (lane >= off) sc += x;
    }
    if (lane == 63) wsum[wv] = sc;
    __syncthreads();
    int prefix = 0;
#pragma unroll
    for (int k = 0; k < 8; ++k) {
        int s = wsum[k];
        prefix += (k < wv) ? s : 0;
    }
    int run = prefix + sc - ts;  // exclusive prefix of ts
    loff[2 * t]     = run;
    loff[2 * t + 1] = run + v0;
#pragma unroll
    for (int k = 0; k < 2; ++k) {
        int b  = 2 * t + k;
        int vvk = (k == 0) ? v0 : v1;
        if (b < nb && vvk > 0) {
            int old = atomicAdd(&bucket_cursor[b], vvk);   // delta in bucket
            ldelta[b] = b * BCAP + old - loff[b];
        }
    }
    __syncthreads();
#pragma unroll
    for (int k = 0; k < 2; ++k) {
        int i4 = t + k * P1_DIM;
        if (i4 < full4) {
            int u4[4] = {uu[k].x, uu[k].y, uu[k].z, uu[k].w};
            int v4[4] = {vv[k].x, vv[k].y, vv[k].z, vv[k].w};
#pragma unroll
            for (int e = 0; e < 4; ++e) {
                int ub = u4[e] >> NB_SHIFT;
                int s1 = loff[ub] + rka[4 * k + e];
                stage[s1]  = ((u4[e] & 255) << 18) | v4[e];
                bstage[s1] = (unsigned short)ub;
                int vb = v4[e] >> NB_SHIFT;
                int s2 = loff[vb] + rkb[4 * k + e];
                stage[s2]  = ((v4[e] & 255) << 18) | u4[e];
                bstage[s2] = (unsigned short)vb;
            }
        }
    }
    if (has_rem) {
        int ub = ur >> NB_SHIFT;
        int s1 = loff[ub] + rkra;
        stage[s1]  = ((ur & 255) << 18) | vr;
        bstage[s1] = (unsigned short)ub;
        int vb = vr >> NB_SHIFT;
        int s2 = loff[vb] + rkrb;
        stage[s2]  = ((vr & 255) << 18) | ur;
        bstage[s2] = (unsigned short)vb;
    }
    __syncthreads();
    int total = 2 * cnt_here;
    for (int s = t; s < total; s += P1_DIM) {
        tmp[s + ldelta[bstage[s]]] = stage[s];
    }
}

// ---- per-bucket finalize: self-prefix, row_ptr, dis/dis2/invd, cv ----
// R3: 512 threads (8 waves) per bucket — halves hist/rank trip counts and
// doubles resident waves vs the 256-thread version. Y0 convert moved to its
// own streaming kernel.
__global__ __launch_bounds__(512) void finalize_kernel(
    const int* __restrict__ tmp, const int* __restrict__ bcur,
    int* __restrict__ row_ptr, float* __restrict__ dis,
    float* __restrict__ dis2, float* __restrict__ invd,
    int* __restrict__ cv, int n_nodes, int nb, int nnz) {
    __shared__ int rcnt[256];
    __shared__ int ccur[256];   // global write cursor per row
    __shared__ int wsum[4];
    __shared__ int red[512];
    int b = blockIdx.x;
    int t = threadIdx.x;
    int lane = t & 63, wv = t >> 6;
    // exclusive prefix of bcur over buckets < b
    int partial = 0;
    for (int i = t; i < b; i += 512) partial += bcur[i];
    red[t] = partial;
    __syncthreads();
    for (int off = 256; off > 0; off >>= 1) {
        if (t < off) red[t] += red[t + off];
        __syncthreads();
    }
    int dbeg  = red[0];
    int count = bcur[b];
    int src   = b * BCAP;
    if (t < 256) rcnt[t] = 0;
    __syncthreads();
    for (int i = t; i < count; i += 512) {
        atomicAdd(&rcnt[tmp[src + i] >> 18], 1);
    }
    __syncthreads();
    // scan over 256 row counts (waves 0..3 fully active -> safe shuffles)
    int v = 0, sc = 0;
    if (t < 256) {
        v  = rcnt[t];
        sc = v;
#pragma unroll
        for (int off = 1; off < 64; off <<= 1) {
            int x = __shfl_up(sc, off);
            if (lane >= off) sc += x;
        }
        if (lane == 63) wsum[wv] = sc;
    }
    __syncthreads();
    if (t < 256) {
        int prefix = 0;
#pragma unroll
        for (int k = 0; k < 4; ++k) {
            int s = wsum[k];
            prefix += (k < wv) ? s : 0;
        }
        int ex = prefix + sc - v;
        ccur[t] = dbeg + ex;       // global cursor -> rank writes direct
        int row = (b << NB_SHIFT) + t;
        if (row < n_nodes) {
            row_ptr[row] = dbeg + ex;
            double dv = (double)v;
            dis[row]  = (v > 0) ? (float)(1.0 / sqrt(dv)) : 0.0f;
            dis2[row] = (v > 0) ? (float)(1.0 / dv) : 0.0f;
            invd[row] = (v > 0) ? (float)sqrt(dv) : 0.0f;
        }
    }
    if (b == nb - 1 && t == 0) row_ptr[n_nodes] = nnz;
    __syncthreads();
    // rank + direct cv write: dest window ~28KB -> L2 write-merge
    for (int i = t; i < count; i += 512) {
        int p  = tmp[src + i];
        int rk = atomicAdd(&ccur[p >> 18], 1);
        cv[rk] = p & 0x3FFFF;
    }
}

// ---- streaming Y0 convert: Y0[row] = dis[row] * X0[row] (fp16, 128B rows)
// one half8 (8 dims) per thread; fully parallel, BW-bound (~58 MB).
__global__ __launch_bounds__(256) void convert_y0_kernel(
    const float4* __restrict__ ut4, const float4* __restrict__ it4,
    const float* __restrict__ dis, half8* __restrict__ Yh0,
    int usernum, int n_nodes) {
    int idx = blockIdx.x * 256 + threadIdx.x;
    int row = idx >> 3;
    if (row >= n_nodes) return;
    int c = idx & 7;
    float d = dis[row];
    const float4* srcp = (row <= usernum)
        ? (ut4 + (size_t)row * 16 + 2 * c)
        : (it4 + (size_t)(row - usernum) * 16 + 2 * c);
    float4 a = srcp[0];
    float4 e = srcp[1];
    half8 o;
    o[0] = (_Float16)(d * a.x); o[1] = (_Float16)(d * a.y);
    o[2] = (_Float16)(d * a.z); o[3] = (_Float16)(d * a.w);
    o[4] = (_Float16)(d * e.x); o[5] = (_Float16)(d * e.y);
    o[6] = (_Float16)(d * e.z); o[7] = (_Float16)(d * e.w);
    Yh0[(size_t)row * 8 + c] = o;
}

// ---- pure gather-sum CSR row: 8 edge-slots x 8 lanes x half8 ----
// (used by gather_logits only) Halving-butterfly reduction: returns ONE
// element per lane, for dim d = l8*8 + k with k = (g&1)*4 + (g&2) + (g>>2).
__device__ inline float csr_row_sum_h(const _Float16* __restrict__ Yh,
                                      const int* __restrict__ cv,
                                      int beg, int end, int g, int l8,
                                      float one) {
    float acc[8] = {0.f, 0.f, 0.f, 0.f, 0.f, 0.f, 0.f, 0.f};
    const char* Yb = (const char*)Yh;
    const char* cb = (const char*)cv;
    unsigned lo = (unsigned)l8 * 16u;
    int j = beg + g;
    for (; j + 8 < end; j += 16) {
        unsigned c0 = (unsigned)*(const int*)(cb + ((unsigned)j << 2));
        unsigned c1 = (unsigned)*(const int*)(cb + ((unsigned)(j + 8) << 2));
        half8 x0 = *(const half8*)(Yb + (c0 << 7) + lo);
        half8 x1 = *(const half8*)(Yb + (c1 << 7) + lo);
        half8 tt = x0 + x1;   // 4x v_pk_add_f16
#pragma unroll
        for (int k = 0; k < 8; ++k) {
            acc[k] += one * (float)tt[k];   // v_mad_mix_f32
        }
    }
    if (j < end) {
        unsigned c0 = (unsigned)*(const int*)(cb + ((unsigned)j << 2));
        half8 x0 = *(const half8*)(Yb + (c0 << 7) + lo);
#pragma unroll
        for (int k = 0; k < 8; ++k) {
            acc[k] += one * (float)x0[k];
        }
    }
    bool gb0 = (g & 1) != 0;
    bool gb1 = (g & 2) != 0;
    bool gb2 = (g & 4) != 0;
    float s0 = gb0 ? acc[0] : acc[4];
    float s1 = gb0 ? acc[1] : acc[5];
    float s2 = gb0 ? acc[2] : acc[6];
    float s3 = gb0 ? acc[3] : acc[7];
    float a0 = (gb0 ? acc[4] : acc[0]) + __shfl_xor(s0, 8);
    float a1 = (gb0 ? acc[5] : acc[1]) + __shfl_xor(s1, 8);
    float a2 = (gb0 ? acc[6] : acc[2]) + __shfl_xor(s2, 8);
    float a3 = (gb0 ? acc[7] : acc[3]) + __shfl_xor(s3, 8);
    float t0 = gb1 ? a0 : a2;
    float t1 = gb1 ? a1 : a3;
    float b0 = (gb1 ? a2 : a0) + __shfl_xor(t0, 16);
    float b1 = (gb1 ? a3 : a1) + __shfl_xor(t1, 16);
    float u = gb2 ? b0 : b1;
    float fin = (gb2 ? b1 : b0) + __shfl_xor(u, 32);
    return fin;
}

__device__ inline int lane_dim(int g, int l8) {
    return l8 * 8 + ((g & 1) * 4 + (g & 2) + (g >> 2));
}

// ---- SpMM: 8 rows per wave, 8 lanes per row, 8 dims per lane ----
// Y_{l+1}[r][d] = dis2[r] * sum_e Y_l[cv[e]][d]
// Lane (g=lane>>3, sub=lane&7) owns dims [8*sub, 8*sub+8) of row wid*8+g and
// accumulates in registers -> no cross-lane reduction at all.
// Edge loop: 8 edges per batch, trip count = wave-max degree (3 shuffles,
// one-time) -> countable loop, no per-iter __any. Out-of-range edge slots
// cndmask to column 0 (node 0 has degree 0 => Y[0][:] == 0 in every layer;
// its single line stays L1-hot => dummy gathers ~free). cv indices for the
// NEXT batch are loaded at the end of the body so the cv->gather dependency
// hides under the current batch's accumulate (counted vmcnt, no full drain).
// cv must be readable ~8KB past nnz (padded in the workspace alloc); garbage
// reads there are masked before use as gather addresses.
__global__ __launch_bounds__(256) void spmm_y_kernel(
    const _Float16* __restrict__ Yin, _Float16* __restrict__ Yout,
    const int* __restrict__ row_ptr, const int* __restrict__ cv,
    const float* __restrict__ dis2, float one, int n_nodes) {
    int wid  = (blockIdx.x * blockDim.x + threadIdx.x) >> 6;
    int lane = threadIdx.x & 63;
    int g = lane >> 3, sub = lane & 7;
    int row = wid * 8 + g;
    bool ok = row < n_nodes;
    int beg = 0, end = 0;
    if (ok) {
        beg = row_ptr[row];
        end = row_ptr[row + 1];
    }
    float d2 = ok ? dis2[row] : 0.0f;
    const char* Yb = (const char*)Yin;
    const char* cb = (const char*)cv;
    unsigned lo = (unsigned)sub * 16u;
    float acc[8] = {0.f, 0.f, 0.f, 0.f, 0.f, 0.f, 0.f, 0.f};
    // wave-max degree -> uniform trip count (lanes within a group agree)
    int len = end - beg;
    int mx = len;
    mx = max(mx, __shfl_xor(mx, 8));
    mx = max(mx, __shfl_xor(mx, 16));
    mx = max(mx, __shfl_xor(mx, 32));
    int iters = (mx + 7) >> 3;
    int j = beg;
    size_t jb = ((size_t)(unsigned)j) << 2;
    int r0 = *(const int*)(cb + jb);
    int r1 = *(const int*)(cb + jb + 4u);
    int r2 = *(const int*)(cb + jb + 8u);
    int r3 = *(const int*)(cb + jb + 12u);
    int r4 = *(const int*)(cb + jb + 16u);
    int r5 = *(const int*)(cb + jb + 20u);
    int r6 = *(const int*)(cb + jb + 24u);
    int r7 = *(const int*)(cb + jb + 28u);
    for (int it = 0; it < iters; ++it) {
        unsigned c0 = (unsigned)((j     < end) ? r0 : 0);
        unsigned c1 = (unsigned)((j + 1 < end) ? r1 : 0);
        unsigned c2 = (unsigned)((j + 2 < end) ? r2 : 0);
        unsigned c3 = (unsigned)((j + 3 < end) ? r3 : 0);
        unsigned c4 = (unsigned)((j + 4 < end) ? r4 : 0);
        unsigned c5 = (unsigned)((j + 5 < end) ? r5 : 0);
        unsigned c6 = (unsigned)((j + 6 < end) ? r6 : 0);
        unsigned c7 = (unsigned)((j + 7 < end) ? r7 : 0);
        half8 x0 = *(const half8*)(Yb + ((size_t)c0 << 7) + lo);
        half8 x1 = *(const half8*)(Yb + ((size_t)c1 << 7) + lo);
        half8 x2 = *(const half8*)(Yb + ((size_t)c2 << 7) + lo);
        half8 x3 = *(const half8*)(Yb + ((size_t)c3 << 7) + lo);
        half8 x4 = *(const half8*)(Yb + ((size_t)c4 << 7) + lo);
        half8 x5 = *(const half8*)(Yb + ((size_t)c5 << 7) + lo);
        half8 x6 = *(const half8*)(Yb + ((size_t)c6 << 7) + lo);
        half8 x7 = *(const half8*)(Yb + ((size_t)c7 << 7) + lo);
        // prefetch next batch's indices (pad-safe past nnz; masked above)
        j += 8;
        jb = ((size_t)(unsigned)j) << 2;
        r0 = *(const int*)(cb + jb);
        r1 = *(const int*)(cb + jb + 4u);
        r2 = *(const int*)(cb + jb + 8u);
        r3 = *(const int*)(cb + jb + 12u);
        r4 = *(const int*)(cb + jb + 16u);
        r5 = *(const int*)(cb + jb + 20u);
        r6 = *(const int*)(cb + jb + 24u);
        r7 = *(const int*)(cb + jb + 28u);
        // pairwise fp16 tree (consumes gathers as they complete, counted
        // vmcnt), then one mad_mix per dim into f32 acc
        half8 sA = (x0 + x1) + (x2 + x3);
        half8 sB = (x4 + x5) + (x6 + x7);
        half8 tt = sA + sB;
#pragma unroll
        for (int k = 0; k < 8; ++k) {
            acc[k] += one * (float)tt[k];   // v_mad_mix_f32
        }
    }
    if (ok) {
        half8 o;
#pragma unroll
        for (int k = 0; k < 8; ++k) o[k] = (_Float16)(acc[k] * d2);
        *(half8*)((char*)Yout + ((size_t)row << 7) + lo) = o;
    }
}

// fused layer-3 + gather + logits: one wave per batch element.
// emb(idx)[d] = X0fp32[idx][d] + invd*(Y1+Y2)[idx][d] + dis*rowdot(Y2)[d];
// out[b] = <emb(u), emb(pos)>/16; out[B+b] = <emb(u), emb(neg)>/16.
__global__ __launch_bounds__(256) void gather_logits_kernel(
    const float* __restrict__ ut, const float* __restrict__ itb,
    const _Float16* __restrict__ Y1, const _Float16* __restrict__ Y2,
    const int* __restrict__ row_ptr, const int* __restrict__ cv,
    const float* __restrict__ dis, const float* __restrict__ invd,
    const int* __restrict__ user_ids, const int* __restrict__ pos_seqs,
    const int* __restrict__ neg_seqs, float* __restrict__ out,
    float one, int usernum, int itemnum, int batch) {
    int w    = (blockIdx.x * blockDim.x + threadIdx.x) >> 6;
    int lane = threadIdx.x & 63;
    if (w >= batch) return;
    int g = lane >> 3, l8 = lane & 7;
    int d = lane_dim(g, l8);
    int idxs[3];
    int u = min(max(user_ids[w], 0), usernum);
    idxs[0] = u;
    int p = min(max(pos_seqs[w], 1), itemnum);
    idxs[1] = usernum + p;
    int nn = min(max(neg_seqs[w], 1), itemnum);
    idxs[2] = usernum + nn;
    float vals[3];
#pragma unroll
    for (int q = 0; q < 3; ++q) {
        int idx = idxs[q];
        int beg = row_ptr[idx];
        int end = row_ptr[idx + 1];
        float dr = dis[idx];
        float iv = invd[idx];
        float fin = csr_row_sum_h(Y2, cv, beg, end, g, l8, one);
        const float* base0 = (q == 0) ? (ut + (size_t)u * 64)
                                      : (itb + (size_t)(idx - usernum) * 64);
        float x0v = base0[d];
        float y1v = (float)Y1[(size_t)idx * 64 + d];
        float y2v = (float)Y2[(size_t)idx * 64 + d];
        vals[q] = x0v + iv * (y1v + y2v) + fin * dr;
    }
    float dp = vals[0] * vals[1];
    float dn = vals[0] * vals[2];
#pragma unroll
    for (int off = 1; off < 64; off <<= 1) {
        dp += __shfl_xor(dp, off);
        dn += __shfl_xor(dn, off);
    }
    if (lane == 0) {
        out[w]         = dp * 0.0625f;
        out[batch + w] = dn * 0.0625f;
    }
}

extern "C" void kernel_launch(void* const* d_in, const int* in_sizes, int n_in,
                              void* d_out, int out_size, void* d_ws,
                              size_t ws_size, hipStream_t stream) {
    const float* user_table = (const float*)d_in[0];
    const float* item_table = (const float*)d_in[1];
    const int*   rows       = (const int*)d_in[3];
    const int*   cols       = (const int*)d_in[4];
    const int*   user_ids   = (const int*)d_in[5];
    const int*   pos_seqs   = (const int*)d_in[6];
    const int*   neg_seqs   = (const int*)d_in[7];
    float*       out        = (float*)d_out;

    const int D = 64;
    int usernum = in_sizes[0] / D - 1;   // 100000
    int itemnum = in_sizes[1] / D - 1;   // 50000
    int nnz     = in_sizes[2];           // 4,000,000
    int batch   = in_sizes[5];           // 4096
    int n_nodes = usernum + itemnum + 1; // 150001
    int nb      = (n_nodes + (1 << NB_SHIFT) - 1) >> NB_SHIFT;  // 586
    int M       = nnz >> 1;              // 2,000,000 source pairs (mirror COO)

    // ---- workspace layout ----
    char* w = (char*)d_ws;
    auto alloc = [&](size_t bytes) {
        char* p = w;
        w += (bytes + 255) & ~(size_t)255;
        return p;
    };
    _Float16* Yh0   = (_Float16*)alloc((size_t)n_nodes * D * 2);  // 19.2 MB
    _Float16* Yh1   = (_Float16*)alloc((size_t)n_nodes * D * 2);  // 19.2 MB
    _Float16* Yh2   = (_Float16*)alloc((size_t)n_nodes * D * 2);  // 19.2 MB
    int*   cv       = (int*)alloc((size_t)nnz * 4 + 8192);        // 16 MB (+pad
                                      // so spmm's wave-max edge loop can read
                                      // cv indices past nnz safely; values
                                      // are masked before use)
    int*   row_ptr  = (int*)alloc((size_t)(n_nodes + 1) * 4);
    float* dis      = (float*)alloc((size_t)n_nodes * 4);
    float* dis2     = (float*)alloc((size_t)n_nodes * 4);
    float* invd     = (float*)alloc((size_t)n_nodes * 4);
    int*   bcur     = (int*)alloc(4096);
    // partition scratch: 586*16000*4 = 37.5 MB, aliases Yh1+Yh2 (38.4 MB);
    // dead after finalize; Yh1/Yh2 written only afterwards.
    int*   tmp      = (int*)Yh1;

    // ---- CSR build ----
    hipMemsetAsync(bcur, 0, 4096, stream);
    int p1_tiles = (M + P1_SRC - 1) / P1_SRC;
    partition_kernel<<<p1_tiles, P1_DIM, 0, stream>>>(rows, cols, bcur, tmp,
                                                      M, nb);
    finalize_kernel<<<nb, 512, 0, stream>>>(tmp, bcur, row_ptr, dis, dis2,
                                            invd, cv, n_nodes, nb, nnz);
    int conv_blocks = (n_nodes * 8 + 255) / 256;
    convert_y0_kernel<<<conv_blocks, 256, 0, stream>>>(
        (const float4*)user_table, (const float4*)item_table, dis,
        (half8*)Yh0, usernum, n_nodes);

    // ---- layers: Yh0 -> Yh1 -> Yh2 (pure gather-sum + 1/deg scale) ----
    const float one = 1.0f;
    int spmm_grid = (n_nodes + 31) / 32;   // 32 rows per 256-thr block
    spmm_y_kernel<<<spmm_grid, 256, 0, stream>>>(Yh0, Yh1, row_ptr, cv, dis2,
                                                 one, n_nodes);
    spmm_y_kernel<<<spmm_grid, 256, 0, stream>>>(Yh1, Yh2, row_ptr, cv, dis2,
                                                 one, n_nodes);

    // ---- fused layer-3 + gather + logits ----
    gather_logits_kernel<<<(batch + 3) / 4, 256, 0, stream>>>(
        user_table, item_table, Yh1, Yh2, row_ptr, cv, dis, invd, user_ids,
        pos_seqs, neg_seqs, out, one, usernum, itemnum, batch);
}